// Round 5
// baseline (162.053 us; speedup 1.0000x reference)
//
#include <hip/hip_runtime.h>

#define IC 3
#define OCH 16
#define IDD 16
#define IHH 32
#define IWW 32
#define ODD 31
#define OHH 63
#define OWW 63
#define NB 32
#define LOG2E 1.44269504088896340736f
#define LN2 0.69314718055994530942f

// native 1-instruction transcendentals (v_exp_f32 / v_log_f32 / v_rcp_f32).
// exp2f/logf without -ffast-math lower to multi-instruction OCML calls — that
// was the round-3/4 VALU inflation (3x instruction count).
static __device__ __forceinline__ float fexp2(float x) { return __builtin_amdgcn_exp2f(x); }
static __device__ __forceinline__ float flog2(float x) { return __builtin_amdgcn_logf(x); }
static __device__ __forceinline__ float frcp(float x)  { return __builtin_amdgcn_rcpf(x); }

// Fused ConvTranspose3d(3->16,k3,s2,p1) + channel-LSE + v*sigmoid(v+3)/6 - bias, clip.
// Parity decomposition: thread = 2(oh) x 2(ow) patch at one od; od parity is
// block-uniform -> zero divergence. x hoisted to regs once (prescaled by log2e,
// conv runs in log2 domain). Weights via wave-uniform indices -> s_load/SGPRs.
// No oc chunking: acc[4][16] + xv fit in <=128 VGPRs (launch_bounds cap), so no
// load sinking / rematerialization.
template <int NTAP>
__device__ __forceinline__ void compute_patch(
    const float* __restrict__ x, const float* __restrict__ w,
    float bv, float* __restrict__ out,
    int b, int od, const int (&kd)[NTAP], const int (&id)[NTAP], int i, int j)
{
    const int ih0 = i;
    const int ih1 = min(i + 1, IHH - 1);   // clamped: feeds only unstored oh=63
    const int iw0 = j;
    const int iw1 = min(j + 1, IWW - 1);   // clamped: feeds only unstored ow=63

    // x00,x01,x10,x11 per (tap, ic), prescaled by log2(e)
    float xv[NTAP][IC][4];
    #pragma unroll
    for (int tp = 0; tp < NTAP; ++tp)
        #pragma unroll
        for (int ic = 0; ic < IC; ++ic) {
            const float* __restrict__ xp = x + (((b * IC + ic) * IDD + id[tp]) << 10);
            xv[tp][ic][0] = xp[ih0 * IWW + iw0] * LOG2E;
            xv[tp][ic][1] = xp[ih0 * IWW + iw1] * LOG2E;
            xv[tp][ic][2] = xp[ih1 * IWW + iw0] * LOG2E;
            xv[tp][ic][3] = xp[ih1 * IWW + iw1] * LOG2E;
        }

    float acc[4][OCH];
    #pragma unroll
    for (int p = 0; p < 4; ++p)
        #pragma unroll
        for (int o = 0; o < OCH; ++o) acc[p][o] = 0.0f;

    #pragma unroll
    for (int o = 0; o < OCH; ++o)
        #pragma unroll
        for (int tp = 0; tp < NTAP; ++tp)
            #pragma unroll
            for (int ic = 0; ic < IC; ++ic) {
                // wave-uniform -> scalar loads (9 contiguous dwords)
                const float* __restrict__ wp = w + ((ic * OCH + o) * 3 + kd[tp]) * 9;
                const float w0 = wp[0], w1 = wp[1], w2 = wp[2];
                const float w3 = wp[3], w4 = wp[4], w5 = wp[5];
                const float w6 = wp[6], w7 = wp[7], w8 = wp[8];
                const float x00 = xv[tp][ic][0], x01 = xv[tp][ic][1];
                const float x10 = xv[tp][ic][2], x11 = xv[tp][ic][3];
                // (even oh, even ow): kh=1,kw=1
                acc[0][o] = fmaf(x00, w4, acc[0][o]);
                // (even, odd): kw=0 <- x[.][+1], kw=2 <- x[.][0]
                acc[1][o] = fmaf(x01, w3, fmaf(x00, w5, acc[1][o]));
                // (odd, even): kh=0 <- x[+1][.], kh=2 <- x[0][.]
                acc[2][o] = fmaf(x10, w1, fmaf(x00, w7, acc[2][o]));
                // (odd, odd)
                acc[3][o] = fmaf(x11, w0, fmaf(x10, w2,
                            fmaf(x01, w6, fmaf(x00, w8, acc[3][o]))));
            }

    // LSE in base 2, then hs = v*sigmoid(v+3)/6, clip(hs - bias)
    const int obase = (b * ODD + od) * OHH;
    #pragma unroll
    for (int p = 0; p < 4; ++p) {
        const int oh = 2 * i + (p >> 1);
        const int ow = 2 * j + (p & 1);
        if (oh < OHH && ow < OWW) {
            float s = 0.0f;
            #pragma unroll
            for (int o = 0; o < OCH; ++o) s += fexp2(acc[p][o]);
            const float v  = LN2 * flog2(s);
            const float e  = fexp2(-(v + 3.0f) * LOG2E);
            const float hs = v * frcp(6.0f * (1.0f + e));
            const float r  = fminf(1.0f, fmaxf(-1.0f, hs - bv));
            out[(obase + oh) * OWW + ow] = r;
        }
    }
}

__global__ __launch_bounds__(256, 4) void convt_lse_kernel(
    const float* __restrict__ x, const float* __restrict__ w,
    const float* __restrict__ bias, float* __restrict__ out)
{
    const int j  = threadIdx.x & 31;                       // ow pair: ow = 2j, 2j+1
    const int i  = (threadIdx.x >> 5) + (blockIdx.x << 3); // oh pair: oh = 2i, 2i+1
    const int od = blockIdx.y;                             // [0,31)
    const int b  = blockIdx.z;                             // [0,32)
    const float bv = bias[0];

    if (od & 1) {
        const int kd[2] = {0, 2};
        const int id[2] = {(od + 1) >> 1, (od - 1) >> 1};
        compute_patch<2>(x, w, bv, out, b, od, kd, id, i, j);
    } else {
        const int kd[1] = {1};
        const int id[1] = {od >> 1};
        compute_patch<1>(x, w, bv, out, b, od, kd, id, i, j);
    }
}

extern "C" void kernel_launch(void* const* d_in, const int* in_sizes, int n_in,
                              void* d_out, int out_size, void* d_ws, size_t ws_size,
                              hipStream_t stream) {
    const float* x    = (const float*)d_in[0];
    const float* w    = (const float*)d_in[1];
    const float* bias = (const float*)d_in[2];
    float* out        = (float*)d_out;

    dim3 grid(4, ODD, NB);   // i-chunks x od x batch = 3968 blocks of 256
    dim3 block(256);
    convt_lse_kernel<<<grid, block, 0, stream>>>(x, w, bias, out);
}

// Round 6
// 102.040 us; speedup vs baseline: 1.5881x; 1.5881x over previous
//
#include <hip/hip_runtime.h>

#define IC 3
#define OCH 16
#define IDD 16
#define IHH 32
#define IWW 32
#define ODD 31
#define OHH 63
#define OWW 63
#define NB 32
#define LOG2E 1.44269504088896340736f
#define LN2 0.69314718055994530942f

// native 1-instruction transcendentals (v_exp_f32 / v_log_f32 / v_rcp_f32).
// exp2f/logf without -ffast-math lower to multi-instruction OCML calls (round-4's
// 2.5x VALU inflation). Accuracy ~1 ulp, verified round 5 (absmax unchanged).
static __device__ __forceinline__ float fexp2(float x) { return __builtin_amdgcn_exp2f(x); }
static __device__ __forceinline__ float flog2(float x) { return __builtin_amdgcn_logf(x); }
static __device__ __forceinline__ float frcp(float x)  { return __builtin_amdgcn_rcpf(x); }

// Fused ConvTranspose3d(3->16,k3,s2,p1) + channel-LSE + v*sigmoid(v+3)/6 - bias, clip.
// Parity decomposition: thread = 2(oh) x 2(ow) patch at one od; od parity is
// block-uniform -> zero divergence. x prescaled by log2e (conv in log2 domain).
// Weights via wave-uniform indices -> s_load/SGPRs, zero LDS.
// oc chunked by 8 (running exp2-sum): keeps live set ~50 VGPRs — round 5 proved
// that un-chunking spills acc to scratch (VGPR 32, WRITE_SIZE 2x, dur 2x).
template <int NTAP>
__device__ __forceinline__ void compute_patch(
    const float* __restrict__ x, const float* __restrict__ w,
    float bv, float* __restrict__ out,
    int b, int od, const int (&kd)[NTAP], const int (&id)[NTAP], int i, int j)
{
    const int ih0 = i;
    const int ih1 = min(i + 1, IHH - 1);   // clamped: feeds only unstored oh=63
    const int iw0 = j;
    const int iw1 = min(j + 1, IWW - 1);   // clamped: feeds only unstored ow=63

    // x00,x01,x10,x11 per (tap, ic), prescaled by log2(e)
    float xv[NTAP][IC][4];
    #pragma unroll
    for (int tp = 0; tp < NTAP; ++tp)
        #pragma unroll
        for (int ic = 0; ic < IC; ++ic) {
            const float* __restrict__ xp = x + (((b * IC + ic) * IDD + id[tp]) << 10);
            xv[tp][ic][0] = xp[ih0 * IWW + iw0] * LOG2E;
            xv[tp][ic][1] = xp[ih0 * IWW + iw1] * LOG2E;
            xv[tp][ic][2] = xp[ih1 * IWW + iw0] * LOG2E;
            xv[tp][ic][3] = xp[ih1 * IWW + iw1] * LOG2E;
        }

    float s[4] = {0.0f, 0.0f, 0.0f, 0.0f};

    #pragma unroll 1
    for (int c = 0; c < 2; ++c) {          // oc chunk: oc = 8c .. 8c+7
        float acc[4][8];
        #pragma unroll
        for (int p = 0; p < 4; ++p)
            #pragma unroll
            for (int o = 0; o < 8; ++o) acc[p][o] = 0.0f;

        #pragma unroll
        for (int o = 0; o < 8; ++o)
            #pragma unroll
            for (int tp = 0; tp < NTAP; ++tp)
                #pragma unroll
                for (int ic = 0; ic < IC; ++ic) {
                    // wave-uniform -> scalar loads (9 contiguous dwords)
                    const float* __restrict__ wp =
                        w + ((ic * OCH + (c * 8 + o)) * 3 + kd[tp]) * 9;
                    const float w0 = wp[0], w1 = wp[1], w2 = wp[2];
                    const float w3 = wp[3], w4 = wp[4], w5 = wp[5];
                    const float w6 = wp[6], w7 = wp[7], w8 = wp[8];
                    const float x00 = xv[tp][ic][0], x01 = xv[tp][ic][1];
                    const float x10 = xv[tp][ic][2], x11 = xv[tp][ic][3];
                    // (even oh, even ow): kh=1,kw=1
                    acc[0][o] = fmaf(x00, w4, acc[0][o]);
                    // (even, odd): kw=0 <- x[.][+1], kw=2 <- x[.][0]
                    acc[1][o] = fmaf(x01, w3, fmaf(x00, w5, acc[1][o]));
                    // (odd, even): kh=0 <- x[+1][.], kh=2 <- x[0][.]
                    acc[2][o] = fmaf(x10, w1, fmaf(x00, w7, acc[2][o]));
                    // (odd, odd)
                    acc[3][o] = fmaf(x11, w0, fmaf(x10, w2,
                                fmaf(x01, w6, fmaf(x00, w8, acc[3][o]))));
                }

        #pragma unroll
        for (int p = 0; p < 4; ++p) {
            float t = 0.0f;
            #pragma unroll
            for (int o = 0; o < 8; ++o) t += fexp2(acc[p][o]);
            s[p] += t;
        }
    }

    // v = ln2*log2(sum2); hs = v*sigmoid(v+3)/6; clip(hs - bias)
    const int obase = (b * ODD + od) * OHH;
    #pragma unroll
    for (int p = 0; p < 4; ++p) {
        const int oh = 2 * i + (p >> 1);
        const int ow = 2 * j + (p & 1);
        if (oh < OHH && ow < OWW) {
            const float v  = LN2 * flog2(s[p]);
            const float e  = fexp2(-(v + 3.0f) * LOG2E);
            const float hs = v * frcp(6.0f * (1.0f + e));
            const float r  = fminf(1.0f, fmaxf(-1.0f, hs - bv));
            out[(obase + oh) * OWW + ow] = r;
        }
    }
}

__global__ __launch_bounds__(256, 4) void convt_lse_kernel(
    const float* __restrict__ x, const float* __restrict__ w,
    const float* __restrict__ bias, float* __restrict__ out)
{
    const int j  = threadIdx.x & 31;                       // ow pair: ow = 2j, 2j+1
    const int i  = (threadIdx.x >> 5) + (blockIdx.x << 3); // oh pair: oh = 2i, 2i+1
    const int od = blockIdx.y;                             // [0,31)
    const int b  = blockIdx.z;                             // [0,32)
    const float bv = bias[0];

    if (od & 1) {
        const int kd[2] = {0, 2};
        const int id[2] = {(od + 1) >> 1, (od - 1) >> 1};
        compute_patch<2>(x, w, bv, out, b, od, kd, id, i, j);
    } else {
        const int kd[1] = {1};
        const int id[1] = {od >> 1};
        compute_patch<1>(x, w, bv, out, b, od, kd, id, i, j);
    }
}

extern "C" void kernel_launch(void* const* d_in, const int* in_sizes, int n_in,
                              void* d_out, int out_size, void* d_ws, size_t ws_size,
                              hipStream_t stream) {
    const float* x    = (const float*)d_in[0];
    const float* w    = (const float*)d_in[1];
    const float* bias = (const float*)d_in[2];
    float* out        = (float*)d_out;

    dim3 grid(4, ODD, NB);   // i-chunks x od x batch = 3968 blocks of 256
    dim3 block(256);
    convt_lse_kernel<<<grid, block, 0, stream>>>(x, w, bias, out);
}